// Round 5
// baseline (1267.199 us; speedup 1.0000x reference)
//
#include <hip/hip_runtime.h>
#include <math.h>

#define BB 64
#define TT 4096
#define CC 64

constexpr int L0v = 2048, U0v = 3069, V0v = 1535, P0v = 2048;
constexpr int L1v = 1024, U1v = 1533, V1v = 767,  P1v = 1024;
constexpr int OUTL = 6144;
constexpr long NTOT = (long)BB * TT * CC;
#define VT 63        // v per block
#define XROWS 88     // t rows staged
#define XSTR 68      // float stride (17 float4)

// ---- transpose x[b][t][c] -> xtr[b][c][t], fused global sum/sumsq ----
__global__ __launch_bounds__(256) void transpose_stats(const float* __restrict__ x,
                                                       float* __restrict__ xtr,
                                                       double* __restrict__ part) {
  __shared__ float tile[64][65];
  __shared__ double sd1[256], sd2[256];
  const int tt = blockIdx.x;
  const int b = blockIdx.y;
  const int t0 = tt * 64;
  const long xbase = (long)b * TT * CC + (long)t0 * CC;
  const int tid = threadIdx.x;
  double a = 0, q = 0;
  {
    int c = tid & 63;
    for (int r = tid >> 6; r < 64; r += 4) {
      float v = x[xbase + r * 64 + c];
      tile[r][c] = v;
      a += v; q += (double)v * (double)v;
    }
  }
  sd1[tid] = a; sd2[tid] = q;
  __syncthreads();
  {
    int tl = tid & 63;
    for (int cc = tid >> 6; cc < 64; cc += 4)
      xtr[((long)(b * 64 + cc)) * TT + t0 + tl] = tile[tl][cc];
  }
  for (int s = 128; s > 0; s >>= 1) {
    if (tid < s) { sd1[tid] += sd1[tid + s]; sd2[tid] += sd2[tid + s]; }
    __syncthreads();
  }
  if (tid == 0) {
    part[(b * 64 + tt) * 2] = sd1[0];
    part[(b * 64 + tt) * 2 + 1] = sd2[0];
  }
}

// ---------------- closed-form index helpers ----------------
__device__ __host__ inline int pad_idx(int p, int brk, int dup, int sub) {
  if (p < brk) { int q = p / 3; int r = p - 3 * q; return 2 * q + (r == 2 ? 1 : 0); }
  if (p < brk + 2) return dup;
  return p - sub;
}

__device__ inline int fmap_code(int k) {
  if (k == 0) return 2048 + 0;
  if (k == 1) return 0;
  if (k < 5462) {
    int m = k - 2;
    int c = m / 12;
    int j = m - 12 * c;
    if (j <= 3)  return 2048 + (1 + 9 * c + j);
    if (j == 4)  return 1 + 3 * c;
    if (j <= 8)  return 2048 + (9 * c + j);
    if (j == 9)  return 2 + 3 * c;
    if (j == 10) return 2048 + (9 + 9 * c);
    return 3 + 3 * c;
  }
  return k - 4096;
}

// ---- merged prep: block 0 = stats_final, 1..64 = weight_norm, 65..88 = codes ----
__global__ __launch_bounds__(256) void prep(const double* __restrict__ part,
                                            double* __restrict__ stats,
                                            const float* __restrict__ v,
                                            const float* __restrict__ g,
                                            float* __restrict__ wt,
                                            int* __restrict__ codes) {
  const int blk = blockIdx.x;
  const int tid = threadIdx.x;
  if (blk == 0) {
    __shared__ double s1[256], s2[256];
    double a = 0, q = 0;
    for (int i = tid; i < 4096; i += 256) { a += part[2 * i]; q += part[2 * i + 1]; }
    s1[tid] = a; s2[tid] = q;
    __syncthreads();
    for (int s = 128; s > 0; s >>= 1) {
      if (tid < s) { s1[tid] += s1[tid + s]; s2[tid] += s2[tid + s]; }
      __syncthreads();
    }
    if (tid == 0) {
      double n = (double)NTOT;
      double mean = s1[0] / n;
      double var = (s2[0] - s1[0] * s1[0] / n) / (n - 1.0);
      stats[0] = mean; stats[1] = sqrt(var);
      stats[2] = 0.8 / mean;
      stats[3] = 0.8 / sqrt(var);
    }
  } else if (blk <= 64) {
    int o = blk - 1;
    __shared__ float red[256];
    __shared__ float scale;
    float vv = (tid < 192) ? v[o * 192 + tid] : 0.f;
    red[tid] = vv * vv;
    __syncthreads();
    for (int s = 128; s > 0; s >>= 1) {
      if (tid < s) red[tid] += red[tid + s];
      __syncthreads();
    }
    if (tid == 0) scale = g[o] / sqrtf(red[0]);
    __syncthreads();
    if (tid < 192) {
      int i = tid / 3, k = tid - 3 * i;
      wt[(k * 64 + i) * 64 + o] = scale * vv;
    }
  } else {
    int k = (blk - 65) * 256 + tid;
    if (k < OUTL) {
      int s = fmap_code(k);
      int type, xi, yi = 0;
      if (s < 2048) {
        if ((s & 1) == 0) { type = 0; xi = 2 * s; }
        else { int p = s >> 1; yi = pad_idx(p, 768, 512, 257); xi = 4 * p + 3; type = 2; }
      } else {
        int p = s - 2048;
        if ((p & 1) == 0) { type = 0; xi = p; }
        else { int q = p >> 1; yi = pad_idx(q, 1536, 1024, 513); xi = 2 * q + 1; type = 1; }
      }
      codes[k] = type | (xi << 2) | (yi << 14);
    }
  }
}

// ---- fused conv + bias + maxpool + elu + gauss + BN-partial-stats ----
// 2 u-slots per lane (weight amortization), x0/x1 staged, phases formed per-lane,
// maxpool via shuffles, BN sums via wave-reduce + float atomics.
__global__ __launch_bounds__(256, 3) void conv_pool(
    const float* __restrict__ x, const float* __restrict__ wt,
    const float* __restrict__ cbias, const double* __restrict__ stats,
    float* __restrict__ y1, float* __restrict__ bnAcc,
    int L, int U, int V, int mult, int off1, int mid) {
  const int b = blockIdx.x;
  const int v0 = blockIdx.y * VT;
  const int tid = threadIdx.x;
  const int lane = tid & 63;
  const int og = __builtin_amdgcn_readfirstlane((tid >> 6) * 16);

  const int u0 = 2 * v0 - 1;
  const int uv_lo = max(u0, 0);
  const int uv_hi = min(u0 + 126, U - 1);
  const int t_lo = (2 * uv_lo) / 3;
  int t_hi = (2 * uv_hi + 6) / 3;
  if (t_hi > L - 1) t_hi = L - 1;
  const int rows = t_hi - t_lo + 1;     // <= 88

  __shared__ float sX[2 * XROWS * XSTR];
  float* X0f = sX;
  float* X1f = sX + XROWS * XSTR;

  const float inv_mean = (float)stats[2];
  const float inv_std  = (float)stats[3];
  const long xbase = (long)b * TT * CC;

  // stage x0/x1 (vectorized float4)
  for (int idx = tid; idx < rows * 16; idx += 256) {
    int tr = idx >> 4, c4 = idx & 15;
    int t = t_lo + tr;
    float4 v0x = *(const float4*)&x[xbase + (long)(mult * t) * CC + 4 * c4];
    float4 v1x = *(const float4*)&x[xbase + (long)(mult * t + off1) * CC + 4 * c4];
    *(float4*)&X0f[tr * XSTR + 4 * c4] = v0x;
    *(float4*)&X1f[tr * XSTR + 4 * c4] = v1x;
  }
  __syncthreads();

  // per-slot setup
  const int uA = u0 + lane, uB = u0 + 64 + lane;
  const int ucA = min(max(uA, 0), U - 1);
  const int ucB = min(uB, U - 1);
  const int t0A = (2 * ucA) / 3, t0B = (2 * ucB) / 3;
  const int rA = 2 * ucA - 3 * t0A, rB = 2 * ucB - 3 * t0B;
  const int trA = t0A - t_lo, trB = t0B - t_lo;
  const float aA = (rA == 0) ? inv_mean : ((rA == 2) ? inv_std : 0.f);
  const float cA = (rA == 1) ? 1.f : 0.2f;
  const float aB = (rB == 0) ? inv_mean : ((rB == 2) ? inv_std : 0.f);
  const float cB = (rB == 1) ? 1.f : 0.2f;

  const float4* X04 = (const float4*)X0f;
  const float4* X14 = (const float4*)X1f;
  const int baseA = trA * 17, baseB = trB * 17;

  float accA[16], accB[16];
  {
    const float* cb_s = cbias + og;
#pragma unroll
    for (int o = 0; o < 16; o++) { accA[o] = cb_s[o]; accB[o] = cb_s[o]; }
  }

#pragma unroll
  for (int k = 0; k < 3; k++) {
    const float* wk = wt + k * 4096 + og;
    const int ra = baseA + k * 17, rb = baseB + k * 17;
#pragma unroll 4
    for (int i4 = 0; i4 < 16; i4++) {
      float4 a0 = X04[ra + i4], a1 = X14[ra + i4];
      float4 b0 = X04[rb + i4], b1 = X14[rb + i4];
      float4 jA, jB;
      jA.x = fmaf(aA, a1.x, cA * a0.x); jA.y = fmaf(aA, a1.y, cA * a0.y);
      jA.z = fmaf(aA, a1.z, cA * a0.z); jA.w = fmaf(aA, a1.w, cA * a0.w);
      jB.x = fmaf(aB, b1.x, cB * b0.x); jB.y = fmaf(aB, b1.y, cB * b0.y);
      jB.z = fmaf(aB, b1.z, cB * b0.z); jB.w = fmaf(aB, b1.w, cB * b0.w);
      const float* wp = wk + i4 * 256;
#pragma unroll
      for (int o = 0; o < 16; o++) {
        float w0 = wp[o], w1 = wp[64 + o], w2 = wp[128 + o], w3 = wp[192 + o];
        accA[o] = fmaf(jA.x, w0, accA[o]);
        accA[o] = fmaf(jA.y, w1, accA[o]);
        accA[o] = fmaf(jA.z, w2, accA[o]);
        accA[o] = fmaf(jA.w, w3, accA[o]);
        accB[o] = fmaf(jB.x, w0, accB[o]);
        accB[o] = fmaf(jB.y, w1, accB[o]);
        accB[o] = fmaf(jB.z, w2, accB[o]);
        accB[o] = fmaf(jB.w, w3, accB[o]);
      }
    }
  }

  // mask invalid u slots
  const bool vA = (uA >= 0) && (uA < U);
  const bool vB = (uB < U);
#pragma unroll
  for (int o = 0; o < 16; o++) {
    if (!vA) accA[o] = -INFINITY;
    if (!vB) accB[o] = -INFINITY;
  }

  // epilogue: lane = v-local; taps at local u-index 2*lane .. 2*lane+2
  const int vl = lane;
  const int v = v0 + vl;
  const bool vvalid = (vl < VT) && (v < V);
  const float wgt = vvalid ? ((v < mid) ? (float)(2 - (v & 1)) : ((v == mid) ? 2.f : 1.f)) : 0.f;
  const int s0 = (2 * vl) & 63, s1 = (2 * vl + 1) & 63, s2 = (2 * vl + 2) & 63;
  const bool f0 = (2 * vl) < 64, f1 = (2 * vl + 1) < 64, f2 = (2 * vl + 2) < 64;
  const long ybase = ((long)(b * 64 + og)) * V + v;

#pragma unroll
  for (int o = 0; o < 16; o++) {
    float tA0 = __shfl(accA[o], s0), tB0 = __shfl(accB[o], s0);
    float tA1 = __shfl(accA[o], s1), tB1 = __shfl(accB[o], s1);
    float tA2 = __shfl(accA[o], s2), tB2 = __shfl(accB[o], s2);
    float m0 = f0 ? tA0 : tB0;
    float m1 = f1 ? tA1 : tB1;
    float m2 = f2 ? tA2 : tB2;
    float m = fmaxf(fmaxf(m0, m1), m2);
    float e = (m > 0.f) ? m : (expf(m) - 1.f);
    float y = expf(-0.5f * e * e);
    if (vvalid) y1[ybase + (long)o * V] = y;
    float ws = wgt * y;
    float wq = ws * y;
    for (int off = 32; off > 0; off >>= 1) {
      ws += __shfl_xor(ws, off);
      wq += __shfl_xor(wq, off);
    }
    if (lane == 0) {
      atomicAdd(&bnAcc[(og + o) * 2], ws);
      atomicAdd(&bnAcc[(og + o) * 2 + 1], wq);
    }
  }
}

// ---- bn final -> affine coefficients: z = A*y + B ----
__global__ __launch_bounds__(128) void bn_final(const float* __restrict__ bnAcc,
                                                const float* __restrict__ gamma,
                                                const float* __restrict__ beta,
                                                float* __restrict__ cf0,
                                                float* __restrict__ cf1) {
  int t = threadIdx.x;
  int lvl = t >> 6, c = t & 63;
  const float* A = bnAcc + lvl * 128;
  double n = lvl ? (double)BB * P1v : (double)BB * P0v;
  double S = A[2 * c], Q = A[2 * c + 1];
  double mu = S / n;
  double var = Q / n - mu * mu;
  float rsig = 1.0f / sqrtf((float)var + 1e-5f);
  float Af = gamma[c] * rsig;
  float Bf = beta[c] - (float)mu * Af;
  float* cf = lvl ? cf1 : cf0;
  cf[2 * c] = Af;
  cf[2 * c + 1] = Bf;
}

// ---- fused finalize + sew-up gather: branchless via code table ----
__global__ __launch_bounds__(256) void final_fused(
    const float* __restrict__ xtr, const float* __restrict__ y10,
    const float* __restrict__ y11, const float* __restrict__ cf0,
    const float* __restrict__ cf1, const int* __restrict__ codes,
    float* __restrict__ out) {
  const int bc = blockIdx.y;
  const int k = blockIdx.x * 256 + threadIdx.x;
  const int c = bc & 63;
  const float A0 = cf0[2 * c], B0 = cf0[2 * c + 1];
  const float A1 = cf1[2 * c], B1 = cf1[2 * c + 1];
  const float* xr  = xtr + (long)bc * TT;
  const float* y0r = y10 + (long)bc * V0v;
  const float* y1r = y11 + (long)bc * V1v;

  int code = codes[k];
  int type = code & 3;
  int xi = (code >> 2) & 4095;
  int yi = code >> 14;
  float xv = xr[xi];
  const float* yrow = (type == 2) ? y1r : y0r;
  float yv = yrow[yi];
  float A = (type == 0) ? 0.f : ((type == 2) ? A1 : A0);
  float Bv = (type == 0) ? 0.f : ((type == 2) ? B1 : B0);
  float z = fmaf(A, yv, Bv);
  float e = (z > 0.f) ? z : (expf(z) - 1.f);
  out[(long)bc * OUTL + k] = xv + e;
}

extern "C" void kernel_launch(void* const* d_in, const int* in_sizes, int n_in,
                              void* d_out, int out_size, void* d_ws, size_t ws_size,
                              hipStream_t stream) {
  const float* x   = (const float*)d_in[0];
  const float* cv  = (const float*)d_in[1];
  const float* cg  = (const float*)d_in[2];
  const float* cb  = (const float*)d_in[3];
  const float* gam = (const float*)d_in[4];
  const float* bet = (const float*)d_in[5];
  float* out = (float*)d_out;

  char* ws = (char*)d_ws;
  size_t cur = 0;
  auto alloc = [&](size_t bytes) -> char* {
    char* p = ws + cur;
    cur = (cur + bytes + 255) & ~(size_t)255;
    return p;
  };
  double* part   = (double*)alloc(4096 * 2 * sizeof(double));
  double* stats  = (double*)alloc(4 * sizeof(double));
  float*  wt     = (float*)alloc(3 * 64 * 64 * sizeof(float));
  float*  bnAcc  = (float*)alloc(256 * sizeof(float));   // 2 levels x 64 o x {S,Q}
  float*  cf0    = (float*)alloc(128 * sizeof(float));
  float*  cf1    = (float*)alloc(128 * sizeof(float));
  int*    codes  = (int*)alloc(OUTL * sizeof(int));
  float*  xtr    = (float*)alloc((size_t)BB * CC * TT * sizeof(float));
  float*  y10    = (float*)alloc((size_t)4096 * V0v * sizeof(float));
  float*  y11    = (float*)alloc((size_t)4096 * V1v * sizeof(float));

  hipMemsetAsync(bnAcc, 0, 256 * sizeof(float), stream);
  transpose_stats<<<dim3(64, 64), 256, 0, stream>>>(x, xtr, part);
  prep<<<89, 256, 0, stream>>>(part, stats, cv, cg, wt, codes);

  conv_pool<<<dim3(64, (V0v + VT - 1) / VT), 256, 0, stream>>>(
      x, wt, cb, stats, y10, bnAcc, L0v, U0v, V0v, 2, 1, 1024);
  conv_pool<<<dim3(64, (V1v + VT - 1) / VT), 256, 0, stream>>>(
      x, wt, cb, stats, y11, bnAcc + 128, L1v, U1v, V1v, 4, 3, 512);

  bn_final<<<1, 128, 0, stream>>>(bnAcc, gam, bet, cf0, cf1);

  final_fused<<<dim3(24, 4096), 256, 0, stream>>>(xtr, y10, y11, cf0, cf1, codes, out);
}

// Round 6
// 398.653 us; speedup vs baseline: 3.1787x; 3.1787x over previous
//
#include <hip/hip_runtime.h>
#include <math.h>

#define BB 64
#define TT 4096
#define CC 64

constexpr int L0v = 2048, U0v = 3069, V0v = 1535, P0v = 2048;
constexpr int L1v = 1024, U1v = 1533, V1v = 767,  P1v = 1024;
constexpr int OUTL = 6144;
constexpr long NTOT = (long)BB * TT * CC;
#define VT 63        // pool outputs per block (128 conv outputs)
#define JROWS 88
#define JSTR 68
#define CBSTR 130

// ---- transpose x[b][t][c] -> xtr[b][c][t], fused global sum/sumsq ----
__global__ __launch_bounds__(256) void transpose_stats(const float* __restrict__ x,
                                                       float* __restrict__ xtr,
                                                       double* __restrict__ part) {
  __shared__ float tile[64][65];
  __shared__ double sd1[256], sd2[256];
  const int tt = blockIdx.x;
  const int b = blockIdx.y;
  const int t0 = tt * 64;
  const long xbase = (long)b * TT * CC + (long)t0 * CC;
  const int tid = threadIdx.x;
  double a = 0, q = 0;
  {
    int c = tid & 63;
    for (int r = tid >> 6; r < 64; r += 4) {
      float v = x[xbase + r * 64 + c];
      tile[r][c] = v;
      a += v; q += (double)v * (double)v;
    }
  }
  sd1[tid] = a; sd2[tid] = q;
  __syncthreads();
  {
    int tl = tid & 63;
    for (int cc = tid >> 6; cc < 64; cc += 4)
      xtr[((long)(b * 64 + cc)) * TT + t0 + tl] = tile[tl][cc];
  }
  for (int s = 128; s > 0; s >>= 1) {
    if (tid < s) { sd1[tid] += sd1[tid + s]; sd2[tid] += sd2[tid + s]; }
    __syncthreads();
  }
  if (tid == 0) {
    part[(b * 64 + tt) * 2] = sd1[0];
    part[(b * 64 + tt) * 2 + 1] = sd2[0];
  }
}

// ---------------- closed-form index helpers ----------------
__device__ __host__ inline int pad_idx(int p, int brk, int dup, int sub) {
  if (p < brk) { int q = p / 3; int r = p - 3 * q; return 2 * q + (r == 2 ? 1 : 0); }
  if (p < brk + 2) return dup;
  return p - sub;
}

__device__ inline int fmap_code(int k) {
  if (k == 0) return 2048 + 0;
  if (k == 1) return 0;
  if (k < 5462) {
    int m = k - 2;
    int c = m / 12;
    int j = m - 12 * c;
    if (j <= 3)  return 2048 + (1 + 9 * c + j);
    if (j == 4)  return 1 + 3 * c;
    if (j <= 8)  return 2048 + (9 * c + j);
    if (j == 9)  return 2 + 3 * c;
    if (j == 10) return 2048 + (9 + 9 * c);
    return 3 + 3 * c;
  }
  return k - 4096;
}

// ---- merged prep: block 0 = stats_final, 1..64 = weight_norm, 65..88 = codes ----
__global__ __launch_bounds__(256) void prep(const double* __restrict__ part,
                                            double* __restrict__ stats,
                                            const float* __restrict__ v,
                                            const float* __restrict__ g,
                                            float* __restrict__ wt,
                                            int* __restrict__ codes) {
  const int blk = blockIdx.x;
  const int tid = threadIdx.x;
  if (blk == 0) {
    __shared__ double s1[256], s2[256];
    double a = 0, q = 0;
    for (int i = tid; i < 4096; i += 256) { a += part[2 * i]; q += part[2 * i + 1]; }
    s1[tid] = a; s2[tid] = q;
    __syncthreads();
    for (int s = 128; s > 0; s >>= 1) {
      if (tid < s) { s1[tid] += s1[tid + s]; s2[tid] += s2[tid + s]; }
      __syncthreads();
    }
    if (tid == 0) {
      double n = (double)NTOT;
      double mean = s1[0] / n;
      double var = (s2[0] - s1[0] * s1[0] / n) / (n - 1.0);
      stats[0] = mean; stats[1] = sqrt(var);
      stats[2] = 0.8 / mean;
      stats[3] = 0.8 / sqrt(var);
    }
  } else if (blk <= 64) {
    int o = blk - 1;
    __shared__ float red[256];
    __shared__ float scale;
    float vv = (tid < 192) ? v[o * 192 + tid] : 0.f;
    red[tid] = vv * vv;
    __syncthreads();
    for (int s = 128; s > 0; s >>= 1) {
      if (tid < s) red[tid] += red[tid + s];
      __syncthreads();
    }
    if (tid == 0) scale = g[o] / sqrtf(red[0]);
    __syncthreads();
    if (tid < 192) {
      int i = tid / 3, k = tid - 3 * i;
      wt[(k * 64 + i) * 64 + o] = scale * vv;
    }
  } else {
    int k = (blk - 65) * 256 + tid;
    if (k < OUTL) {
      int s = fmap_code(k);
      int type, xi, yi = 0;
      if (s < 2048) {
        if ((s & 1) == 0) { type = 0; xi = 2 * s; }
        else { int p = s >> 1; yi = pad_idx(p, 768, 512, 257); xi = 4 * p + 3; type = 2; }
      } else {
        int p = s - 2048;
        if ((p & 1) == 0) { type = 0; xi = p; }
        else { int q = p >> 1; yi = pad_idx(q, 1536, 1024, 513); xi = 2 * q + 1; type = 1; }
      }
      codes[k] = type | (xi << 2) | (yi << 14);
    }
  }
}

// ---- fused conv (stride2, dil3) + bias + maxpool(3,s2,p1) + elu + gauss ----
// 2 u-slots per lane; 3 pre-formed J phases in LDS (1 ds_read_b128 per slot per i4);
// weights via SGPR s_load (2 B per FMA). Maxpool via cbf in (reused) LDS.
__global__ __launch_bounds__(256) void conv_pool(
    const float* __restrict__ x, const float* __restrict__ wt,
    const float* __restrict__ cbias, const double* __restrict__ stats,
    float* __restrict__ y1, int L, int U, int V, int mult, int off1) {
  const int b = blockIdx.x;
  const int v0 = blockIdx.y * VT;
  const int tid = threadIdx.x;
  const int lane = tid & 63;
  const int og = __builtin_amdgcn_readfirstlane((tid >> 6) * 16);

  const int u0 = 2 * v0 - 1;
  const int uv_lo = max(u0, 0);
  const int uv_hi = min(u0 + 127, U - 1);
  const int t_lo = (2 * uv_lo) / 3;
  int t_hi = (2 * uv_hi + 6) / 3;
  if (t_hi > L - 1) t_hi = L - 1;
  const int rows = t_hi - t_lo + 1;     // <= 88

  __shared__ float smem[3 * JROWS * JSTR];   // 71808 B; later reused as cbf[64][130]
  float* Jb = smem;
  float* cbf = smem;

  const float inv_mean = (float)stats[2];
  const float inv_std  = (float)stats[3];
  const long xbase = (long)b * TT * CC;

  // stage: form the 3 phase streams
  for (int idx = tid; idx < rows * 16; idx += 256) {
    int tr = idx >> 4, c4 = (idx & 15) * 4;
    int t = t_lo + tr;
    float4 x0 = *(const float4*)&x[xbase + (long)(mult * t) * CC + c4];
    float4 x1 = *(const float4*)&x[xbase + (long)(mult * t + off1) * CC + c4];
    float4 j0, j2;
    j0.x = fmaf(inv_mean, x1.x, 0.2f * x0.x); j0.y = fmaf(inv_mean, x1.y, 0.2f * x0.y);
    j0.z = fmaf(inv_mean, x1.z, 0.2f * x0.z); j0.w = fmaf(inv_mean, x1.w, 0.2f * x0.w);
    j2.x = fmaf(inv_std,  x1.x, 0.2f * x0.x); j2.y = fmaf(inv_std,  x1.y, 0.2f * x0.y);
    j2.z = fmaf(inv_std,  x1.z, 0.2f * x0.z); j2.w = fmaf(inv_std,  x1.w, 0.2f * x0.w);
    *(float4*)&Jb[(0 * JROWS + tr) * JSTR + c4] = j0;
    *(float4*)&Jb[(1 * JROWS + tr) * JSTR + c4] = x0;
    *(float4*)&Jb[(2 * JROWS + tr) * JSTR + c4] = j2;
  }
  __syncthreads();

  const int uA = u0 + lane, uB = uA + 64;
  const int ucA = min(max(uA, 0), U - 1);
  const int ucB = min(uB, U - 1);
  const int t0A = (2 * ucA) / 3, t0B = (2 * ucB) / 3;
  const int rA = 2 * ucA - 3 * t0A, rB = 2 * ucB - 3 * t0B;
  const float* JrowA = Jb + ((rA * JROWS) + (t0A - t_lo)) * JSTR;
  const float* JrowB = Jb + ((rB * JROWS) + (t0B - t_lo)) * JSTR;

  float accA[16], accB[16];
  {
    const float* cb_s = cbias + og;
#pragma unroll
    for (int o = 0; o < 16; o++) { accA[o] = cb_s[o]; accB[o] = cb_s[o]; }
  }

  for (int k = 0; k < 3; k++) {
    const float4* ra = (const float4*)(JrowA + k * JSTR);
    const float4* rb = (const float4*)(JrowB + k * JSTR);
    const float* wk = wt + k * 4096 + og;
#pragma unroll 4
    for (int i4 = 0; i4 < 16; i4++) {
      float4 jA = ra[i4];
      float4 jB = rb[i4];
      const float* wp = wk + i4 * 256;
#pragma unroll
      for (int o = 0; o < 16; o++) {
        float w0 = wp[o], w1 = wp[64 + o], w2 = wp[128 + o], w3 = wp[192 + o];
        accA[o] = fmaf(jA.x, w0, accA[o]);
        accA[o] = fmaf(jA.y, w1, accA[o]);
        accA[o] = fmaf(jA.z, w2, accA[o]);
        accA[o] = fmaf(jA.w, w3, accA[o]);
        accB[o] = fmaf(jB.x, w0, accB[o]);
        accB[o] = fmaf(jB.y, w1, accB[o]);
        accB[o] = fmaf(jB.z, w2, accB[o]);
        accB[o] = fmaf(jB.w, w3, accB[o]);
      }
    }
  }

  const bool mA = (uA >= 0) && (uA < U);
  const bool mB = (uB < U);

  __syncthreads();   // J dead; reuse as cbf[64][130]
#pragma unroll
  for (int o = 0; o < 16; o++) {
    cbf[(og + o) * CBSTR + lane]      = mA ? accA[o] : -INFINITY;
    cbf[(og + o) * CBSTR + 64 + lane] = mB ? accB[o] : -INFINITY;
  }
  __syncthreads();

  if (lane < VT) {
    int v = v0 + lane;
    if (v < V) {
      const long ybase = ((long)(b * 64 + og)) * V + v;
#pragma unroll
      for (int o = 0; o < 16; o++) {
        const float* cr = cbf + (og + o) * CBSTR + 2 * lane;
        float m = fmaxf(fmaxf(cr[0], cr[1]), cr[2]);
        float e = (m > 0.f) ? m : (expf(m) - 1.f);
        y1[ybase + (long)o * V] = expf(-0.5f * e * e);
      }
    }
  }
}

// ---- batchnorm stats: weighted sequential sum (equiv to dpad gather) ----
// weight(v) = 2-(v&1) for v<mid ; 2 at v==mid ; 1 for v>mid
__global__ __launch_bounds__(256) void bn_partial(const float* __restrict__ y1,
                                                  double* __restrict__ part,
                                                  int V, int mid) {
  const int c = blockIdx.x, chunk = blockIdx.y;   // chunk: 8 b's each
  __shared__ double s1[256], s2[256];
  double a = 0, q = 0;
  for (int b = chunk * 8; b < chunk * 8 + 8; b++) {
    const float* row = y1 + ((long)(b * 64 + c)) * V;
    for (int v = threadIdx.x; v < V; v += 256) {
      float val = row[v];
      float w = (v < mid) ? (float)(2 - (v & 1)) : ((v == mid) ? 2.f : 1.f);
      float wv = w * val;
      a += wv; q += (double)wv * (double)val;
    }
  }
  s1[threadIdx.x] = a; s2[threadIdx.x] = q;
  __syncthreads();
  for (int s = 128; s > 0; s >>= 1) {
    if (threadIdx.x < s) { s1[threadIdx.x] += s1[threadIdx.x + s]; s2[threadIdx.x] += s2[threadIdx.x + s]; }
    __syncthreads();
  }
  if (threadIdx.x == 0) {
    part[(c * 8 + chunk) * 2]     = s1[0];
    part[(c * 8 + chunk) * 2 + 1] = s2[0];
  }
}

// ---- bn final -> affine coefficients: z = A*y + B ----
__global__ __launch_bounds__(128) void bn_final(const double* __restrict__ p0,
                                                const double* __restrict__ p1,
                                                const float* __restrict__ gamma,
                                                const float* __restrict__ beta,
                                                float* __restrict__ cf0,
                                                float* __restrict__ cf1) {
  int t = threadIdx.x;
  const double* pp = (t < 64) ? p0 : p1;
  int c = t & 63;
  double n = (t < 64) ? (double)BB * P0v : (double)BB * P1v;
  double a = 0, q = 0;
  for (int j = 0; j < 8; j++) { a += pp[(c * 8 + j) * 2]; q += pp[(c * 8 + j) * 2 + 1]; }
  double mu = a / n;
  double var = q / n - mu * mu;
  float rsig = 1.0f / sqrtf((float)var + 1e-5f);
  float A = gamma[c] * rsig;
  float Bv = beta[c] - (float)mu * A;
  float* cf = (t < 64) ? cf0 : cf1;
  cf[2 * c] = A;
  cf[2 * c + 1] = Bv;
}

// ---- fused finalize + sew-up gather: branchless via code table ----
__global__ __launch_bounds__(256) void final_fused(
    const float* __restrict__ xtr, const float* __restrict__ y10,
    const float* __restrict__ y11, const float* __restrict__ cf0,
    const float* __restrict__ cf1, const int* __restrict__ codes,
    float* __restrict__ out) {
  const int bc = blockIdx.y;
  const int k = blockIdx.x * 256 + threadIdx.x;
  const int c = bc & 63;
  const float A0 = cf0[2 * c], B0 = cf0[2 * c + 1];
  const float A1 = cf1[2 * c], B1 = cf1[2 * c + 1];
  const float* xr  = xtr + (long)bc * TT;
  const float* y0r = y10 + (long)bc * V0v;
  const float* y1r = y11 + (long)bc * V1v;

  int code = codes[k];
  int type = code & 3;
  int xi = (code >> 2) & 4095;
  int yi = code >> 14;
  float xv = xr[xi];
  const float* yrow = (type == 2) ? y1r : y0r;
  float yv = yrow[yi];
  float A = (type == 0) ? 0.f : ((type == 2) ? A1 : A0);
  float Bv = (type == 0) ? 0.f : ((type == 2) ? B1 : B0);
  float z = fmaf(A, yv, Bv);
  float e = (z > 0.f) ? z : (expf(z) - 1.f);
  out[(long)bc * OUTL + k] = xv + e;
}

extern "C" void kernel_launch(void* const* d_in, const int* in_sizes, int n_in,
                              void* d_out, int out_size, void* d_ws, size_t ws_size,
                              hipStream_t stream) {
  const float* x   = (const float*)d_in[0];
  const float* cv  = (const float*)d_in[1];
  const float* cg  = (const float*)d_in[2];
  const float* cb  = (const float*)d_in[3];
  const float* gam = (const float*)d_in[4];
  const float* bet = (const float*)d_in[5];
  float* out = (float*)d_out;

  char* ws = (char*)d_ws;
  size_t cur = 0;
  auto alloc = [&](size_t bytes) -> char* {
    char* p = ws + cur;
    cur = (cur + bytes + 255) & ~(size_t)255;
    return p;
  };
  double* part   = (double*)alloc(4096 * 2 * sizeof(double));
  double* stats  = (double*)alloc(4 * sizeof(double));
  float*  wt     = (float*)alloc(3 * 64 * 64 * sizeof(float));
  double* bnpt0  = (double*)alloc(64 * 8 * 2 * sizeof(double));
  double* bnpt1  = (double*)alloc(64 * 8 * 2 * sizeof(double));
  float*  cf0    = (float*)alloc(128 * sizeof(float));
  float*  cf1    = (float*)alloc(128 * sizeof(float));
  int*    codes  = (int*)alloc(OUTL * sizeof(int));
  float*  xtr    = (float*)alloc((size_t)BB * CC * TT * sizeof(float));
  float*  y10    = (float*)alloc((size_t)4096 * V0v * sizeof(float));
  float*  y11    = (float*)alloc((size_t)4096 * V1v * sizeof(float));

  transpose_stats<<<dim3(64, 64), 256, 0, stream>>>(x, xtr, part);
  prep<<<89, 256, 0, stream>>>(part, stats, cv, cg, wt, codes);

  conv_pool<<<dim3(64, (V0v + VT - 1) / VT), 256, 0, stream>>>(
      x, wt, cb, stats, y10, L0v, U0v, V0v, 2, 1);
  conv_pool<<<dim3(64, (V1v + VT - 1) / VT), 256, 0, stream>>>(
      x, wt, cb, stats, y11, L1v, U1v, V1v, 4, 3);

  bn_partial<<<dim3(64, 8), 256, 0, stream>>>(y10, bnpt0, V0v, 1024);
  bn_partial<<<dim3(64, 8), 256, 0, stream>>>(y11, bnpt1, V1v, 512);
  bn_final<<<1, 128, 0, stream>>>(bnpt0, bnpt1, gam, bet, cf0, cf1);

  final_fused<<<dim3(24, 4096), 256, 0, stream>>>(xtr, y10, y11, cf0, cf1, codes, out);
}